// Round 8
// baseline (73.492 us; speedup 1.0000x reference)
//
#include <hip/hip_runtime.h>
#include <hip/hip_bf16.h>
#include <math.h>

#define SEQ_LEN 32768
#define HID 1024
#define NBLK_E 2048          // energy blocks: 16 rows each
#define SWZ 997              // odd -> (bid*SWZ)&2047 is a bijection on [0,2048)
#define NPASS 3              // MEASUREMENT ROUND: read enc 3x to expose k_energy in rocprof

// ---------------------------------------------------------------------------
// K1: v = W^T h. One block per column (known-good from R2).
// ---------------------------------------------------------------------------
__global__ void __launch_bounds__(256) k_matvec(const float* __restrict__ W,
                                                const float* __restrict__ hvec,
                                                float* __restrict__ v) {
    const int col = blockIdx.x;
    const int t = threadIdx.x;
    float acc = 0.f;
#pragma unroll
    for (int i = 0; i < 4; ++i) {
        const int d = (i << 8) + t;
        acc = fmaf(hvec[d], W[d * HID + col], acc);
    }
#pragma unroll
    for (int off = 32; off; off >>= 1) acc += __shfl_xor(acc, off, 64);
    __shared__ float red[4];
    if ((t & 63) == 0) red[t >> 6] = acc;
    __syncthreads();
    if (t == 0) v[col] = (red[0] + red[1]) + (red[2] + red[3]);
}

// ---------------------------------------------------------------------------
// K2 (measurement build): energies[s] = enc[s,:].v, but the 128 MB enc read
// is performed NPASS times (memory-clobber between passes defeats CSE/LICM;
// energies = sum/NPASS, mathematically identical within ~1e-7 relative).
// Purpose: push dur above the 75 us poison fills so rocprof shows this
// kernel's dur/FETCH_SIZE/hbm_gbps -> measures true streaming read BW and
// L3-residency of enc on replays.
// ---------------------------------------------------------------------------
__global__ void __launch_bounds__(256) k_energy(const float* __restrict__ enc,
                                                const float* __restrict__ v,
                                                float* __restrict__ energies,
                                                float2* __restrict__ bstats) {
    const int t = threadIdx.x;
    const int wave = t >> 6;
    const int lane = t & 63;
    const int chunk = (blockIdx.x * SWZ) & (NBLK_E - 1);
    const int row0 = (chunk << 4) + (wave << 2);

    const float4 vr0 = *reinterpret_cast<const float4*>(v +       (lane << 2));
    const float4 vr1 = *reinterpret_cast<const float4*>(v + 256 + (lane << 2));
    const float4 vr2 = *reinterpret_cast<const float4*>(v + 512 + (lane << 2));
    const float4 vr3 = *reinterpret_cast<const float4*>(v + 768 + (lane << 2));

    float esum[4] = {0.f, 0.f, 0.f, 0.f};

    for (int pass = 0; pass < NPASS; ++pass) {
        asm volatile("" ::: "memory");     // force genuine reloads each pass
#pragma unroll
        for (int r = 0; r < 4; ++r) {
            const float4* p = reinterpret_cast<const float4*>(enc + (size_t)(row0 + r) * HID) + lane;
            const float4 a = p[0];
            const float4 b = p[64];
            const float4 c = p[128];
            const float4 d = p[192];
            float acc = a.x * vr0.x + a.y * vr0.y + a.z * vr0.z + a.w * vr0.w
                      + b.x * vr1.x + b.y * vr1.y + b.z * vr1.z + b.w * vr1.w
                      + c.x * vr2.x + c.y * vr2.y + c.z * vr2.z + c.w * vr2.w
                      + d.x * vr3.x + d.y * vr3.y + d.z * vr3.z + d.w * vr3.w;
#pragma unroll
            for (int off = 32; off; off >>= 1) acc += __shfl_xor(acc, off, 64);
            esum[r] += acc;
        }
    }

    float m = -__builtin_inff();
    float z = 0.f;
    __shared__ float e_lds[16];
#pragma unroll
    for (int r = 0; r < 4; ++r) {
        const float e = esum[r] * (1.f / NPASS);
        if (lane == 0) energies[row0 + r] = e;
        const float nm = fmaxf(m, e);
        z = z * __expf(m - nm) + __expf(e - nm);
        m = nm;
    }

    __shared__ float wm[4], wz[4];
    if (lane == 0) { wm[wave] = m; wz[wave] = z; }
    __syncthreads();
    if (t == 0) {
        float M = fmaxf(fmaxf(wm[0], wm[1]), fmaxf(wm[2], wm[3]));
        float Z = wz[0] * __expf(wm[0] - M) + wz[1] * __expf(wm[1] - M)
                + wz[2] * __expf(wm[2] - M) + wz[3] * __expf(wm[3] - M);
        bstats[chunk] = make_float2(M, Z);
    }
    (void)e_lds;
}

// ---------------------------------------------------------------------------
// K3: reduce 2048 block stats -> (M,Z) redundantly per block, then write
// attn[i] = exp(e[i]-M)/Z. 64 blocks x 256 threads. (unchanged from R7)
// ---------------------------------------------------------------------------
__global__ void __launch_bounds__(256) k_final(const float* __restrict__ energies,
                                               const float2* __restrict__ bstats,
                                               float* __restrict__ out) {
    __shared__ float sm[256], sz[256];
    const int t = threadIdx.x;
    float m = -__builtin_inff();
    float z = 0.f;
#pragma unroll
    for (int i = 0; i < 8; ++i) {
        const float2 s = bstats[t + (i << 8)];
        const float nm = fmaxf(m, s.x);
        z = z * __expf(m - nm) + s.y * __expf(s.x - nm);
        m = nm;
    }
    sm[t] = m; sz[t] = z;
    __syncthreads();
    for (int off = 128; off; off >>= 1) {
        if (t < off) {
            const float m1 = sm[t], z1 = sz[t];
            const float m2 = sm[t + off], z2 = sz[t + off];
            const float M = fmaxf(m1, m2);
            sm[t] = M;
            sz[t] = z1 * __expf(m1 - M) + z2 * __expf(m2 - M);
        }
        __syncthreads();
    }
    const float M = sm[0];
    const float rZ = 1.f / sz[0];

    const size_t i = ((size_t)blockIdx.x << 9) + ((size_t)t << 1);
    const float2 e = *reinterpret_cast<const float2*>(energies + i);
    float2 o;
    o.x = __expf(e.x - M) * rZ;
    o.y = __expf(e.y - M) * rZ;
    *reinterpret_cast<float2*>(out + i) = o;
}

extern "C" void kernel_launch(void* const* d_in, const int* in_sizes, int n_in,
                              void* d_out, int out_size, void* d_ws, size_t ws_size,
                              hipStream_t stream) {
    const float* hidden = (const float*)d_in[0];   // [1,1,1024]
    const float* enc    = (const float*)d_in[1];   // [32768,1024]
    const float* W      = (const float*)d_in[2];   // [1024,1024]
    // d_in[3] (bias) cancels in softmax (constant shift) — never read.

    float* ws       = (float*)d_ws;
    float* v        = ws;                            // 1024 floats
    float* energies = ws + HID;                      // 32768 floats
    float2* bstats  = (float2*)(ws + HID + SEQ_LEN); // 2048 float2

    k_matvec<<<HID, 256, 0, stream>>>(W, hidden, v);
    k_energy<<<NBLK_E, 256, 0, stream>>>(enc, v, energies, bstats);
    k_final<<<SEQ_LEN / 512, 256, 0, stream>>>(energies, bstats, (float*)d_out);
}

// Round 10
// 32.528 us; speedup vs baseline: 2.2593x; 2.2593x over previous
//
#include <hip/hip_runtime.h>
#include <hip/hip_bf16.h>
#include <math.h>

#define SEQ_LEN 32768
#define HID 1024
#define NBLK_E 2048          // energy blocks: 16 rows each
#define SWZ 997              // odd -> (bid*SWZ)&2047 is a bijection on [0,2048)

typedef float f32x4 __attribute__((ext_vector_type(4)));  // native vector: OK for nontemporal builtins

// ---------------------------------------------------------------------------
// K1: v = W^T h, fetch-exact version.
// 32 blocks x 1024 threads. Block b owns cols [32b, 32b+32).
// Thread (dt,ct) = (t>>5, t&31): col = 32b+ct, d in [32dt, 32dt+32).
// A wave's 64 lanes = 2 dt-groups x 32 cols -> each load instr touches
// exactly two FULL 128B lines (no amplification; W fetched once, 4 MB total).
// ---------------------------------------------------------------------------
__global__ void __launch_bounds__(1024) k_matvec(const float* __restrict__ W,
                                                 const float* __restrict__ hvec,
                                                 float* __restrict__ v) {
    const int t = threadIdx.x;
    const int ct = t & 31;
    const int dt = t >> 5;               // 0..31
    const int col = (blockIdx.x << 5) + ct;
    const int d0 = dt << 5;

    float acc = 0.f;
#pragma unroll 8
    for (int i = 0; i < 32; ++i) {
        const int d = d0 + i;
        acc = fmaf(hvec[d], W[(size_t)d * HID + col], acc);
    }

    __shared__ float red[32][33];        // +1 pad: conflict-free column sums
    red[dt][ct] = acc;
    __syncthreads();
    if (t < 32) {
        float s = 0.f;
#pragma unroll
        for (int i = 0; i < 32; ++i) s += red[i][t];
        v[(blockIdx.x << 5) + t] = s;
    }
}

// ---------------------------------------------------------------------------
// K2: energies[s] = enc[s,:] . v  — the 128 MB stream.
// 2048 blocks x 256 threads, swizzled chunk ownership, 2-deep row pipeline.
// enc loads NONTEMPORAL (streaming path, no cache allocation) via native
// ext_vector_type — HIP float4 is a class and rejected by the builtin.
// ---------------------------------------------------------------------------
__global__ void __launch_bounds__(256) k_energy(const float* __restrict__ enc,
                                                const float* __restrict__ v,
                                                float* __restrict__ energies,
                                                float2* __restrict__ bstats) {
    const int t = threadIdx.x;
    const int wave = t >> 6;
    const int lane = t & 63;
    const int chunk = (blockIdx.x * SWZ) & (NBLK_E - 1);
    const int row0 = (chunk << 4) + (wave << 2);

    const f32x4 vr0 = *reinterpret_cast<const f32x4*>(v +       (lane << 2));
    const f32x4 vr1 = *reinterpret_cast<const f32x4*>(v + 256 + (lane << 2));
    const f32x4 vr2 = *reinterpret_cast<const f32x4*>(v + 512 + (lane << 2));
    const f32x4 vr3 = *reinterpret_cast<const f32x4*>(v + 768 + (lane << 2));

    float m = -__builtin_inff();
    float z = 0.f;

    const f32x4* p = reinterpret_cast<const f32x4*>(enc + (size_t)row0 * HID) + lane;
    f32x4 a = __builtin_nontemporal_load(p);
    f32x4 b = __builtin_nontemporal_load(p + 64);
    f32x4 c = __builtin_nontemporal_load(p + 128);
    f32x4 d = __builtin_nontemporal_load(p + 192);

#pragma unroll
    for (int r = 0; r < 4; ++r) {
        f32x4 na, nb, nc, nd;
        if (r < 3) {
            const f32x4* q = p + (size_t)(r + 1) * 256;
            na = __builtin_nontemporal_load(q);
            nb = __builtin_nontemporal_load(q + 64);
            nc = __builtin_nontemporal_load(q + 128);
            nd = __builtin_nontemporal_load(q + 192);
        }
        const f32x4 s4 = a * vr0 + b * vr1 + c * vr2 + d * vr3;
        float acc = (s4.x + s4.y) + (s4.z + s4.w);
#pragma unroll
        for (int off = 32; off; off >>= 1) acc += __shfl_xor(acc, off, 64);
        if (lane == 0) energies[row0 + r] = acc;
        const float nm = fmaxf(m, acc);
        z = z * __expf(m - nm) + __expf(acc - nm);
        m = nm;
        a = na; b = nb; c = nc; d = nd;
    }

    __shared__ float wm[4], wz[4];
    if (lane == 0) { wm[wave] = m; wz[wave] = z; }
    __syncthreads();
    if (t == 0) {
        float M = fmaxf(fmaxf(wm[0], wm[1]), fmaxf(wm[2], wm[3]));
        float Z = wz[0] * __expf(wm[0] - M) + wz[1] * __expf(wm[1] - M)
                + wz[2] * __expf(wm[2] - M) + wz[3] * __expf(wm[3] - M);
        bstats[chunk] = make_float2(M, Z);
    }
}

// ---------------------------------------------------------------------------
// K3: reduce 2048 block stats -> (M,Z) redundantly per block (16 KB, L2-hot),
// then write attn[i] = exp(e[i]-M)/Z. 64 blocks x 256 threads.
// ---------------------------------------------------------------------------
__global__ void __launch_bounds__(256) k_final(const float* __restrict__ energies,
                                               const float2* __restrict__ bstats,
                                               float* __restrict__ out) {
    __shared__ float sm[256], sz[256];
    const int t = threadIdx.x;
    float m = -__builtin_inff();
    float z = 0.f;
#pragma unroll
    for (int i = 0; i < 8; ++i) {
        const float2 s = bstats[t + (i << 8)];
        const float nm = fmaxf(m, s.x);
        z = z * __expf(m - nm) + s.y * __expf(s.x - nm);
        m = nm;
    }
    sm[t] = m; sz[t] = z;
    __syncthreads();
    for (int off = 128; off; off >>= 1) {
        if (t < off) {
            const float m1 = sm[t], z1 = sz[t];
            const float m2 = sm[t + off], z2 = sz[t + off];
            const float M = fmaxf(m1, m2);
            sm[t] = M;
            sz[t] = z1 * __expf(m1 - M) + z2 * __expf(m2 - M);
        }
        __syncthreads();
    }
    const float M = sm[0];
    const float rZ = 1.f / sz[0];

    const size_t i = ((size_t)blockIdx.x << 9) + ((size_t)t << 1);
    const float2 e = *reinterpret_cast<const float2*>(energies + i);
    float2 o;
    o.x = __expf(e.x - M) * rZ;
    o.y = __expf(e.y - M) * rZ;
    *reinterpret_cast<float2*>(out + i) = o;
}

extern "C" void kernel_launch(void* const* d_in, const int* in_sizes, int n_in,
                              void* d_out, int out_size, void* d_ws, size_t ws_size,
                              hipStream_t stream) {
    const float* hidden = (const float*)d_in[0];   // [1,1,1024]
    const float* enc    = (const float*)d_in[1];   // [32768,1024]
    const float* W      = (const float*)d_in[2];   // [1024,1024]
    // d_in[3] (bias) cancels in softmax (constant shift) — never read.

    float* ws       = (float*)d_ws;
    float* v        = ws;                            // 1024 floats
    float* energies = ws + HID;                      // 32768 floats
    float2* bstats  = (float2*)(ws + HID + SEQ_LEN); // 2048 float2

    k_matvec<<<HID / 32, 1024, 0, stream>>>(W, hidden, v);
    k_energy<<<NBLK_E, 256, 0, stream>>>(enc, v, energies, bstats);
    k_final<<<SEQ_LEN / 512, 256, 0, stream>>>(energies, bstats, (float*)d_out);
}